// Round 10
// baseline (228.396 us; speedup 1.0000x reference)
//
#include <hip/hip_runtime.h>
#include <hip/hip_bf16.h>

// MHA: B=2, S=2048, D=1024, H=16, HD=64. fp32 in, fp32 out.
// Swizzled bf16 inter-kernel layouts (16B blocks) so all staging is contiguous DMA:
//   A/W swizzle ([R][K=1024]): block g=((r>>7)*128+(k>>3))*128+(r&127)
//   K_sw/V_sw: block g=((bh*32+kt)*8+kc)*64+row
// ws (>=54MB proven): [0,8)MB Qb | [8,16) Ksw | [16,24) Vsw | [24,30) Wq/k/vt |
//   [30,38) Aq | [38,46) Ak | [46,54) Av. ctx overlays [24,32) after QKV GEMM;
//   Opart [32,48) + Lpart [48,48.5) overlay dead Aq/Ak/Av during fattn;
//   Wot at [0,2) written AFTER fattn_sp (Qb dead) by a separate cvt3 launch.
// Q-proj scale folds 1/sqrt(HD)*log2(e) so fattn uses native exp2.
// R9-R13: fattn ladder 75->65us. R14: DMA GEMMs 241->233. R15/16: KV-split 225.7.
// R17: single-barrier 3-buffer gemms + cvt4 merge -> FAILED absmax 5.75: cvt4 wrote
//   Wot to [50,52) then cvtA's Av [46,54) clobbered it. GEMM schedule audit clean.
// R18 (this): R17 gemms kept; Wot reverted to R16-proven placement ([0,2), separate
//   cvt3 launch after fattn_sp). LESSON: check every overlay against ALL later
//   writers' intervals, not just the consumer chain.

typedef short s16x8 __attribute__((ext_vector_type(8)));
typedef float f32x4v __attribute__((ext_vector_type(4)));
typedef float f32x16v __attribute__((ext_vector_type(16)));
typedef unsigned int u32x4v __attribute__((ext_vector_type(4)));

__device__ inline unsigned short f2bf(float f) {   // RNE (proven R2-R6)
    union { float f; unsigned int i; } x; x.f = f;
    unsigned int r = x.i + 0x7FFFu + ((x.i >> 16) & 1u);
    return (unsigned short)(r >> 16);
}
__device__ inline unsigned int pkbf(float lo, float hi) {  // lo16=bf(lo), hi16=bf(hi)
    return (unsigned int)f2bf(lo) | ((unsigned int)f2bf(hi) << 16);
}
__device__ inline float bf2f(unsigned short u) {
    union { unsigned int i; float f; } x; x.i = (unsigned int)u << 16; return x.f;
}

// async global->LDS, 16B/lane. Global address PER-LANE; LDS base wave-uniform,
// HW writes base + lane*16.
__device__ inline void gld_lds16(const unsigned short* g, unsigned short* l) {
    __builtin_amdgcn_global_load_lds(
        (const __attribute__((address_space(1))) unsigned int*)(const void*)g,
        (__attribute__((address_space(3))) unsigned int*)(void*)l,
        16, 0, 0);
}

// W[K=1024][N=1024] fp32 -> Wt bf16 in A/W swizzle (transpose+convert). z selects tensor.
__global__ __launch_bounds__(256)
void cvt3(const float* __restrict__ W0, const float* __restrict__ W1, const float* __restrict__ W2,
          unsigned short* __restrict__ T0, unsigned short* __restrict__ T1, unsigned short* __restrict__ T2) {
    const float* W = (blockIdx.z == 0) ? W0 : (blockIdx.z == 1) ? W1 : W2;
    unsigned short* Wt = (blockIdx.z == 0) ? T0 : (blockIdx.z == 1) ? T1 : T2;
    __shared__ __align__(16) unsigned short Ls[64 * 72];
    const int t = threadIdx.x;
    const int k0 = blockIdx.y * 64, n0 = blockIdx.x * 64;
    const int r = t >> 4, c4 = (t & 15) * 4;
    #pragma unroll
    for (int i = 0; i < 4; ++i) {
        float4 wv = *(const float4*)&W[(size_t)(k0 + r + i * 16) * 1024 + n0 + c4];
        Ls[(c4 + 0) * 72 + r + i * 16] = f2bf(wv.x);
        Ls[(c4 + 1) * 72 + r + i * 16] = f2bf(wv.y);
        Ls[(c4 + 2) * 72 + r + i * 16] = f2bf(wv.z);
        Ls[(c4 + 3) * 72 + r + i * 16] = f2bf(wv.w);
    }
    __syncthreads();
    #pragma unroll
    for (int i = 0; i < 2; ++i) {
        const int p = i * 256 + t;
        const int n = p & 63, kc = p >> 6;
        s16x8 v = *(const s16x8*)&Ls[n * 72 + kc * 8];
        const int gn = n0 + n, k = k0 + kc * 8;
        const size_t g = ((size_t)(gn >> 7) * 128 + (k >> 3)) * 128 + (gn & 127);
        *(s16x8*)&Wt[g * 8] = v;
    }
}

// A[4096][1024] fp32 -> bf16 A/W swizzle (no transpose). Grid (16 k-tiles, 32 rp, 3 z).
__global__ __launch_bounds__(256)
void cvtA(const float* __restrict__ A0, const float* __restrict__ A1, const float* __restrict__ A2,
          unsigned short* __restrict__ O0, unsigned short* __restrict__ O1, unsigned short* __restrict__ O2) {
    const float* A = (blockIdx.z == 0) ? A0 : (blockIdx.z == 1) ? A1 : A2;
    unsigned short* O = (blockIdx.z == 0) ? O0 : (blockIdx.z == 1) ? O1 : O2;
    __shared__ __align__(16) unsigned short Ls[8192];   // 16 KB
    const int t = threadIdx.x;
    const int k0 = blockIdx.x * 64, rp = blockIdx.y;
    const int row = t >> 1, kh = (t & 1) * 32;
    const float* src = A + (size_t)(rp * 128 + row) * 1024 + k0 + kh;
    float4 f[8];
    #pragma unroll
    for (int i = 0; i < 8; ++i) f[i] = ((const float4*)src)[i];
    #pragma unroll
    for (int j = 0; j < 4; ++j) {
        uint4 u;
        u.x = pkbf(f[j * 2].x, f[j * 2].y);
        u.y = pkbf(f[j * 2].z, f[j * 2].w);
        u.z = pkbf(f[j * 2 + 1].x, f[j * 2 + 1].y);
        u.w = pkbf(f[j * 2 + 1].z, f[j * 2 + 1].w);
        const int kc = (t & 1) * 4 + j;
        *(uint4*)&Ls[(kc * 128 + row) * 8] = u;
    }
    __syncthreads();
    const size_t gbase = ((size_t)rp * 128 + (k0 >> 3)) * 128;
    #pragma unroll
    for (int i = 0; i < 4; ++i) {
        const int idx = i * 256 + t;
        *(uint4*)&O[(gbase + idx) * 8] = *(const uint4*)&Ls[idx * 8];
    }
}

// QKV GEMM: C = A_bf16 @ W^T, both operands DMA. 128x128 tile, BK=32.
// 3-buffer (48KB) single-barrier counted-vmcnt: per kt {vmcnt(4); barrier;
// stage(kt+2)->(kt+2)%3; compute buf kt%3}. 3 blocks/CU; grid 768 = one round;
// XCD chunk 96.
__global__ __launch_bounds__(256, 3)
void gemm_qkv(const unsigned short* __restrict__ Aq, const unsigned short* __restrict__ Ak,
              const unsigned short* __restrict__ Av,
              const unsigned short* __restrict__ W0, const unsigned short* __restrict__ W1,
              const unsigned short* __restrict__ W2,
              unsigned short* __restrict__ OQ, unsigned short* __restrict__ OK,
              unsigned short* __restrict__ OV, float scaleQ) {
    const int p = blockIdx.x;
    const int L = (p & 7) * 96 + (p >> 3);          // 768 = 8 XCD x 96
    const int z = L >> 8;
    const int rem = L & 255;
    const int m0 = (rem >> 3) * 128, n0 = (rem & 7) * 128;
    const unsigned short* Asw = (z == 0) ? Aq : (z == 1) ? Ak : Av;
    const unsigned short* Bsw = (z == 0) ? W0 : (z == 1) ? W1 : W2;
    const float scale = (z == 0) ? scaleQ : 1.0f;

    __shared__ __align__(16) unsigned short Al[3][4096];   // 3 x 8KB
    __shared__ __align__(16) unsigned short Bl[3][4096];   // 3 x 8KB
    const int t = threadIdx.x, lane = t & 63, w = t >> 6;
    const int ln = lane & 15, qd = lane >> 4;
    const int mw = (w & 1) * 64, nw = (w >> 1) * 64;
    const size_t gaB = (size_t)(m0 >> 7) * 16384;
    const size_t gbB = (size_t)(n0 >> 7) * 16384;

    f32x4v acc[4][4] = {};

    auto stage = [&](int kt, int b) {   // 2 A + 2 B gld_lds16 per thread = 4 vm/wave
        const size_t ga = gaB + (size_t)kt * 512;
        const size_t gb = gbB + (size_t)kt * 512;
        #pragma unroll
        for (int j = 0; j < 2; ++j)
            gld_lds16(Asw + (ga + j * 256 + t) * 8, &Al[b][(j * 256 + w * 64) * 8]);
        #pragma unroll
        for (int j = 0; j < 2; ++j)
            gld_lds16(Bsw + (gb + j * 256 + t) * 8, &Bl[b][(j * 256 + w * 64) * 8]);
    };

    stage(0, 0);
    stage(1, 1);
    int cur = 0;
    for (int kt = 0; kt < 32; ++kt) {
        if (kt < 31) asm volatile("s_waitcnt vmcnt(4)" ::: "memory");
        else         asm volatile("s_waitcnt vmcnt(0)" ::: "memory");
        __builtin_amdgcn_s_barrier();       // all waves' tile-kt DMA landed;
        asm volatile("" ::: "memory");      // compute(kt-1) readers fenced
        if (kt < 30) {
            const int ib = (cur == 0) ? 2 : cur - 1;   // (kt+2)%3
            stage(kt + 2, ib);
        }
        {
            s16x8 a[4], bb[4];
            #pragma unroll
            for (int mt = 0; mt < 4; ++mt)
                a[mt] = *(const s16x8*)&Al[cur][(qd * 128 + mw + mt * 16 + ln) * 8];
            #pragma unroll
            for (int nt = 0; nt < 4; ++nt)
                bb[nt] = *(const s16x8*)&Bl[cur][(qd * 128 + nw + nt * 16 + ln) * 8];
            #pragma unroll
            for (int mt = 0; mt < 4; ++mt)
                #pragma unroll
                for (int nt = 0; nt < 4; ++nt)
                    acc[mt][nt] = __builtin_amdgcn_mfma_f32_16x16x32_bf16(a[mt], bb[nt], acc[mt][nt], 0, 0, 0);
        }
        cur = (cur == 2) ? 0 : cur + 1;
    }

    #pragma unroll
    for (int mt = 0; mt < 4; ++mt)
        #pragma unroll
        for (int nt = 0; nt < 4; ++nt)
            #pragma unroll
            for (int i = 0; i < 4; ++i) {
                const int m = m0 + mw + mt * 16 + qd * 4 + i;
                const int n = n0 + nw + nt * 16 + ln;
                const float v = acc[mt][nt][i] * scale;
                const int bh = (m >> 11) * 16 + (n >> 6), s = m & 2047, hd = n & 63;
                if (z == 0) {
                    OQ[((size_t)bh * 2048 + s) * 64 + hd] = f2bf(v);
                } else if (z == 1) {
                    const size_t g = ((size_t)(bh * 32 + (s >> 6)) * 8 + (hd >> 3)) * 64 + (s & 63);
                    OK[g * 8 + (hd & 7)] = f2bf(v);
                } else {
                    const size_t g = ((size_t)(bh * 32 + (s >> 6)) * 8 + ((s >> 3) & 7)) * 64 + hd;
                    OV[g * 8 + (s & 7)] = f2bf(v);
                }
            }
}

// Output GEMM: out = ctx_sw @ Wot^T. 128x64 tile, BK=64.
// 3-buffer (72KB) single-barrier counted vmcnt(6). 2 blocks/CU; grid 512 = one
// round; XCD chunk 64.
__global__ __launch_bounds__(256, 2)
void gemm_out(const unsigned short* __restrict__ Asw, const unsigned short* __restrict__ Bsw,
              float* __restrict__ outF) {
    const int p = blockIdx.x;
    const int L = (p & 7) * 64 + (p >> 3);          // 512 = 8 XCD x 64
    const int m0 = (L >> 4) * 128, n0 = (L & 15) * 64;

    __shared__ __align__(16) unsigned short Al[3][8192];   // 3 x 16KB
    __shared__ __align__(16) unsigned short Bl[3][4096];   // 3 x 8KB
    const int t = threadIdx.x, lane = t & 63, w = t >> 6;
    const int ln = lane & 15, qd = lane >> 4;
    const int mw = (w & 1) * 64, nw = (w >> 1) * 32;
    const size_t gaB = (size_t)(m0 >> 7) * 16384;
    const size_t gbB = (size_t)(n0 >> 7) * 16384 + (n0 & 127);

    f32x4v acc[4][2] = {};

    auto stage = [&](int kt, int b) {   // 4 A + 2 B gld_lds16 per thread = 6 vm/wave
        const size_t ga = gaB + (size_t)kt * 1024;
        #pragma unroll
        for (int j = 0; j < 4; ++j)
            gld_lds16(Asw + (ga + j * 256 + t) * 8, &Al[b][(j * 256 + w * 64) * 8]);
        #pragma unroll
        for (int i = 0; i < 2; ++i) {
            const int c = w * 2 + i;
            const size_t gb = gbB + (size_t)(kt * 8 + c) * 128 + lane;
            gld_lds16(Bsw + gb * 8, &Bl[b][(c * 64) * 8]);
        }
    };

    stage(0, 0);
    stage(1, 1);
    int cur = 0;
    for (int kt = 0; kt < 16; ++kt) {
        if (kt < 15) asm volatile("s_waitcnt vmcnt(6)" ::: "memory");
        else         asm volatile("s_waitcnt vmcnt(0)" ::: "memory");
        __builtin_amdgcn_s_barrier();
        asm volatile("" ::: "memory");
        if (kt < 14) {
            const int ib = (cur == 0) ? 2 : cur - 1;   // (kt+2)%3
            stage(kt + 2, ib);
        }
        #pragma unroll
        for (int kk = 0; kk < 2; ++kk) {
            const int kc = kk * 4 + qd;
            s16x8 a[4], bb[2];
            #pragma unroll
            for (int mt = 0; mt < 4; ++mt)
                a[mt] = *(const s16x8*)&Al[cur][(kc * 128 + mw + mt * 16 + ln) * 8];
            #pragma unroll
            for (int nt = 0; nt < 2; ++nt)
                bb[nt] = *(const s16x8*)&Bl[cur][(kc * 64 + nw + nt * 16 + ln) * 8];
            #pragma unroll
            for (int mt = 0; mt < 4; ++mt)
                #pragma unroll
                for (int nt = 0; nt < 2; ++nt)
                    acc[mt][nt] = __builtin_amdgcn_mfma_f32_16x16x32_bf16(a[mt], bb[nt], acc[mt][nt], 0, 0, 0);
        }
        cur = (cur == 2) ? 0 : cur + 1;
    }

    #pragma unroll
    for (int mt = 0; mt < 4; ++mt)
        #pragma unroll
        for (int nt = 0; nt < 2; ++nt)
            #pragma unroll
            for (int i = 0; i < 4; ++i) {
                const int m = m0 + mw + mt * 16 + qd * 4 + i;
                const int n = n0 + nw + nt * 16 + ln;
                outF[(size_t)m * 1024 + n] = acc[mt][nt][i];
            }
}

// Flash attention (R15, unchanged): KV-split=2, swapped QK^T, cvt_pk+permlane P-frags,
// rowsum via MFMA ones-B. 2-buffer 32KB, two-barrier counted vmcnt(4), 4 blocks/CU.
__device__ __forceinline__ void fa_compute(
        const unsigned short* Ksb, const unsigned short* Vsb,
        const int H, const int l31, const s16x8* qf,
        f32x16v* accO, f32x16v& accL) {
    f32x16v accS[2] = {};
    #pragma unroll
    for (int kk = 0; kk < 4; ++kk) {
        s16x8 kf0 = *(const s16x8*)&Ksb[((kk * 2 + H) * 64 + l31) * 8];
        s16x8 kf1 = *(const s16x8*)&Ksb[((kk * 2 + H) * 64 + 32 + l31) * 8];
        accS[0] = __builtin_amdgcn_mfma_f32_32x32x16_bf16(kf0, qf[kk], accS[0], 0, 0, 0);
        accS[1] = __builtin_amdgcn_mfma_f32_32x32x16_bf16(kf1, qf[kk], accS[1], 0, 0, 0);
    }

    u32x4v af[4];
    #pragma unroll
    for (int mt = 0; mt < 2; ++mt) {
        float p[16];
        #pragma unroll
        for (int r = 0; r < 16; ++r)
            p[r] = exp2f(accS[mt][r]);
        unsigned int C[8];
        #pragma unroll
        for (int j = 0; j < 8; ++j)
            asm("v_cvt_pk_bf16_f32 %0, %1, %2" : "=v"(C[j]) : "v"(p[2 * j]), "v"(p[2 * j + 1]));
        #pragma unroll
        for (int pp = 0; pp < 2; ++pp) {
            unsigned int x0 = C[4 * pp + 0], y0 = C[4 * pp + 2];
            unsigned int x1 = C[4 * pp + 1], y1 = C[4 * pp + 3];
            asm("v_permlane32_swap_b32 %0, %1" : "+v"(x0), "+v"(y0));
            asm("v_permlane32_swap_b32 %0, %1" : "+v"(x1), "+v"(y1));
            u32x4v a; a.x = x0; a.y = x1; a.z = y0; a.w = y1;
            af[mt * 2 + pp] = a;
        }
    }

    const s16x8 ones = {(short)0x3F80, (short)0x3F80, (short)0x3F80, (short)0x3F80,
                        (short)0x3F80, (short)0x3F80, (short)0x3F80, (short)0x3F80};
    #pragma unroll
    for (int kk2 = 0; kk2 < 4; ++kk2) {
        s16x8 a = __builtin_bit_cast(s16x8, af[kk2]);
        s16x8 vf0 = *(const s16x8*)&Vsb[((kk2 * 2 + H) * 64 + l31) * 8];
        s16x8 vf1 = *(const s16x8*)&Vsb[((kk2 * 2 + H) * 64 + 32 + l31) * 8];
        accO[0] = __builtin_amdgcn_mfma_f32_32x32x16_bf16(a, vf0, accO[0], 0, 0, 0);
        accO[1] = __builtin_amdgcn_mfma_f32_32x32x16_bf16(a, vf1, accO[1], 0, 0, 0);
        accL    = __builtin_amdgcn_mfma_f32_32x32x16_bf16(a, ones, accL, 0, 0, 0);
    }
}

__global__ __launch_bounds__(256, 4)
void fattn_sp(const unsigned short* __restrict__ Q, const unsigned short* __restrict__ Ksw,
              const unsigned short* __restrict__ Vsw, unsigned short* __restrict__ Opart,
              float* __restrict__ Lpart) {
    __shared__ __align__(16) unsigned short Ks2[2][4096];
    __shared__ __align__(16) unsigned short Vs2[2][4096];

    const int t = threadIdx.x, lane = t & 63, w = t >> 6;
    const int l31 = lane & 31, H = lane >> 5;
    const int bid = blockIdx.x;
    const int wid = (bid & 7) * 128 + (bid >> 3);   // 1024 = 8 XCD x 128
    const int bh = wid >> 5, inner = wid & 31;
    const int split = inner >> 4, mblk = inner & 15;
    const int m0 = mblk * 128;
    const size_t head = (size_t)bh * 2048 * 64;

    s16x8 qf[4];
    #pragma unroll
    for (int kk = 0; kk < 4; ++kk)
        qf[kk] = *(const s16x8*)(Q + head + (size_t)(m0 + w * 32 + l31) * 64 + kk * 16 + H * 8);
    asm volatile("s_waitcnt vmcnt(0)" ::: "memory");
    #pragma unroll
    for (int kk = 0; kk < 4; ++kk) {
        u32x4v q = __builtin_bit_cast(u32x4v, qf[kk]);
        asm volatile("" : "+v"(q.x), "+v"(q.y), "+v"(q.z), "+v"(q.w));
        qf[kk] = __builtin_bit_cast(s16x8, q);
    }

    const size_t tb = (size_t)(bh * 32 + split * 16) * 512;
    auto stage = [&](int kt, int b) {   // 4 vm-ops per wave
        const size_t tk = tb + (size_t)kt * 512;
        #pragma unroll
        for (int j = 0; j < 2; ++j)
            gld_lds16(Ksw + (tk + j * 256 + t) * 8, &Ks2[b][(j * 256 + w * 64) * 8]);
        #pragma unroll
        for (int j = 0; j < 2; ++j)
            gld_lds16(Vsw + (tk + j * 256 + t) * 8, &Vs2[b][(j * 256 + w * 64) * 8]);
    };

    stage(0, 0);
    stage(1, 1);

    f32x16v accO[2] = {};
    f32x16v accL = {};

    for (int kt = 0; kt < 16; ++kt) {
        if (kt < 15) asm volatile("s_waitcnt vmcnt(4)" ::: "memory");
        else         asm volatile("s_waitcnt vmcnt(0)" ::: "memory");
        __builtin_amdgcn_s_barrier();
        asm volatile("" ::: "memory");
        fa_compute(Ks2[kt & 1], Vs2[kt & 1], H, l31, qf, accO, accL);
        if (kt < 14) {
            __builtin_amdgcn_s_barrier();   // all waves done reading buf kt&1
            asm volatile("" ::: "memory");
            stage(kt + 2, kt & 1);
        }
    }

    // dump partials: accO as bf16 (per-thread 64B), accL f32 (per (w,H), lanes l31==0)
    const int lb = bh * 16 + mblk;
    unsigned int Wd[16];
    #pragma unroll
    for (int nt = 0; nt < 2; ++nt)
        #pragma unroll
        for (int r = 0; r < 16; r += 2)
            Wd[nt * 8 + r / 2] = pkbf(accO[nt][r], accO[nt][r + 1]);
    uint4* od = (uint4*)(Opart + ((size_t)(split * 512 + lb) * 256 + t) * 32);
    od[0] = *(const uint4*)&Wd[0];
    od[1] = *(const uint4*)&Wd[4];
    od[2] = *(const uint4*)&Wd[8];
    od[3] = *(const uint4*)&Wd[12];
    if (l31 == 0) {
        float lv[16];
        #pragma unroll
        for (int r = 0; r < 16; ++r) lv[r] = accL[r];
        float4* ld = (float4*)(Lpart + (((size_t)(split * 512 + lb) * 4 + w) * 2 + H) * 16);
        ld[0] = *(const float4*)&lv[0];
        ld[1] = *(const float4*)&lv[4];
        ld[2] = *(const float4*)&lv[8];
        ld[3] = *(const float4*)&lv[12];
    }
}

// Combine: ctx = (O0 + O1) / (L0 + L1), written in A/W swizzle. Grid 512 x 256.
__global__ __launch_bounds__(256)
void fa_comb(const unsigned short* __restrict__ Opart, const float* __restrict__ Lpart,
             unsigned short* __restrict__ ctx) {
    const int lb = blockIdx.x, t = threadIdx.x;
    const int lane = t & 63, w = t >> 6;
    const int l31 = lane & 31, H = lane >> 5;
    const int bh = lb >> 4, m0 = (lb & 15) * 128;

    const float* L0 = Lpart + (((size_t)lb * 4 + w) * 2 + H) * 16;
    const float* L1 = Lpart + (((size_t)(512 + lb) * 4 + w) * 2 + H) * 16;
    float inv[16];
    #pragma unroll
    for (int r = 0; r < 16; ++r) inv[r] = 1.f / (L0[r] + L1[r]);

    const uint4* o0 = (const uint4*)(Opart + ((size_t)lb * 256 + t) * 32);
    const uint4* o1 = (const uint4*)(Opart + ((size_t)(512 + lb) * 256 + t) * 32);
    unsigned int A0[16], A1[16];
    *(uint4*)&A0[0] = o0[0]; *(uint4*)&A0[4] = o0[1];
    *(uint4*)&A0[8] = o0[2]; *(uint4*)&A0[12] = o0[3];
    *(uint4*)&A1[0] = o1[0]; *(uint4*)&A1[4] = o1[1];
    *(uint4*)&A1[8] = o1[2]; *(uint4*)&A1[12] = o1[3];

    #pragma unroll
    for (int r = 0; r < 16; ++r) {
        const int qloc = (r & 3) + 8 * (r >> 2) + 4 * H;
        const int mrow = (bh >> 4) * 2048 + m0 + w * 32 + qloc;
        #pragma unroll
        for (int nt = 0; nt < 2; ++nt) {
            const int j = nt * 16 + r;
            const unsigned int w0 = A0[j >> 1], w1 = A1[j >> 1];
            const unsigned short h0 = (j & 1) ? (unsigned short)(w0 >> 16) : (unsigned short)(w0 & 0xFFFF);
            const unsigned short h1 = (j & 1) ? (unsigned short)(w1 >> 16) : (unsigned short)(w1 & 0xFFFF);
            const float out = (bf2f(h0) + bf2f(h1)) * inv[r];
            const int k = (bh & 15) * 64 + nt * 32 + l31;
            const size_t g = ((size_t)(mrow >> 7) * 128 + (k >> 3)) * 128 + (mrow & 127);
            ctx[g * 8 + (k & 7)] = f2bf(out);
        }
    }
}

extern "C" void kernel_launch(void* const* d_in, const int* in_sizes, int n_in,
                              void* d_out, int out_size, void* d_ws, size_t ws_size,
                              hipStream_t stream) {
    char* ws = (char*)d_ws;
    unsigned short* Qb    = (unsigned short*)(ws);
    unsigned short* Ksw   = (unsigned short*)(ws + ((size_t)8 << 20));
    unsigned short* Vsw   = (unsigned short*)(ws + ((size_t)16 << 20));
    unsigned short* Wqt   = (unsigned short*)(ws + ((size_t)24 << 20));
    unsigned short* Wkt   = (unsigned short*)(ws + ((size_t)26 << 20));
    unsigned short* Wvt   = (unsigned short*)(ws + ((size_t)28 << 20));
    unsigned short* Aq    = (unsigned short*)(ws + ((size_t)30 << 20));
    unsigned short* Ak    = (unsigned short*)(ws + ((size_t)38 << 20));
    unsigned short* Av    = (unsigned short*)(ws + ((size_t)46 << 20));
    unsigned short* ctx   = (unsigned short*)(ws + ((size_t)24 << 20));  // after QKV GEMM
    unsigned short* Opart = (unsigned short*)(ws + ((size_t)32 << 20));  // overlays dead Aq/Ak
    float*          Lpart = (float*)         (ws + ((size_t)48 << 20));  // overlays dead Av
    unsigned short* Wot   = (unsigned short*)(ws);                        // [0,2): Qb dead after fattn_sp

    cvt3<<<dim3(16, 16, 3), 256, 0, stream>>>((const float*)d_in[3], (const float*)d_in[4],
                                              (const float*)d_in[5], Wqt, Wkt, Wvt);

    cvtA<<<dim3(16, 32, 3), 256, 0, stream>>>((const float*)d_in[0], (const float*)d_in[1],
                                              (const float*)d_in[2], Aq, Ak, Av);
    gemm_qkv<<<dim3(768), 256, 0, stream>>>(Aq, Ak, Av, Wqt, Wkt, Wvt,
                                            Qb, Ksw, Vsw, 0.125f * 1.44269504f);

    fattn_sp<<<dim3(1024), 256, 0, stream>>>(Qb, Ksw, Vsw, Opart, Lpart);

    cvt3<<<dim3(16, 16, 1), 256, 0, stream>>>((const float*)d_in[6], nullptr, nullptr,
                                              Wot, nullptr, nullptr);

    fa_comb<<<dim3(512), 256, 0, stream>>>(Opart, Lpart, ctx);

    gemm_out<<<dim3(512), 256, 0, stream>>>(ctx, Wot, (float*)d_out);
}

// Round 13
// 222.417 us; speedup vs baseline: 1.0269x; 1.0269x over previous
//
#include <hip/hip_runtime.h>
#include <hip/hip_bf16.h>

// MHA: B=2, S=2048, D=1024, H=16, HD=64. fp32 in, fp32 out.
// Swizzled bf16 inter-kernel layouts (16B blocks) so all staging is contiguous DMA:
//   A/W swizzle ([R][K=1024]): block g=((r>>7)*128+(k>>3))*128+(r&127)
//   K_sw/V_sw: block g=((bh*32+kt)*8+kc)*64+row
// ws (>=54MB proven): [0,8)MB Qb | [8,16) Ksw | [16,24) Vsw | [24,30) Wq/k/vt |
//   [30,38) Aq | [38,46) Ak | [46,54) Av. ctx overlays [24,32) after QKV GEMM;
//   Opart [32,48) + Lpart [48,48.5) overlay dead Aq/Ak/Av during fattn;
//   Wot at [0,2) written AFTER fattn_sp (Qb dead) by a separate cvt3 launch.
// Q-proj scale folds 1/sqrt(HD)*log2(e) so fattn uses native exp2 range.
// R9-R13: fattn ladder 75->65us. R14: DMA GEMMs 241->233. R15/16: KV-split+ones-B
//   rowsum: 225.73us (BEST PASSING). R17/18: 3-buf single-barrier gemms neutral
//   (228.4); Wot overlay bug found+fixed (lesson: check overlays against ALL later
//   writers). R19/R20: native v_exp_f32 (inline asm AND __builtin_amdgcn_exp2f)
//   BOTH fail absmax ~0.05 vs exp2f's 0.0015 -> OCML exp2f wrapper is numerically
//   load-bearing here; v_exp_f32 is NOT a drop-in. Mechanism unresolved; exp2f
//   is now frozen. R21 (this): revert to exact R16 best-passing configuration.

typedef short s16x8 __attribute__((ext_vector_type(8)));
typedef float f32x4v __attribute__((ext_vector_type(4)));
typedef float f32x16v __attribute__((ext_vector_type(16)));
typedef unsigned int u32x4v __attribute__((ext_vector_type(4)));

__device__ inline unsigned short f2bf(float f) {   // RNE (proven R2-R6)
    union { float f; unsigned int i; } x; x.f = f;
    unsigned int r = x.i + 0x7FFFu + ((x.i >> 16) & 1u);
    return (unsigned short)(r >> 16);
}
__device__ inline unsigned int pkbf(float lo, float hi) {  // lo16=bf(lo), hi16=bf(hi)
    return (unsigned int)f2bf(lo) | ((unsigned int)f2bf(hi) << 16);
}
__device__ inline float bf2f(unsigned short u) {
    union { unsigned int i; float f; } x; x.i = (unsigned int)u << 16; return x.f;
}

// async global->LDS, 16B/lane. Global address PER-LANE; LDS base wave-uniform,
// HW writes base + lane*16.
__device__ inline void gld_lds16(const unsigned short* g, unsigned short* l) {
    __builtin_amdgcn_global_load_lds(
        (const __attribute__((address_space(1))) unsigned int*)(const void*)g,
        (__attribute__((address_space(3))) unsigned int*)(void*)l,
        16, 0, 0);
}

// W[K=1024][N=1024] fp32 -> Wt bf16 in A/W swizzle (transpose+convert). z selects tensor.
__global__ __launch_bounds__(256)
void cvt3(const float* __restrict__ W0, const float* __restrict__ W1, const float* __restrict__ W2,
          unsigned short* __restrict__ T0, unsigned short* __restrict__ T1, unsigned short* __restrict__ T2) {
    const float* W = (blockIdx.z == 0) ? W0 : (blockIdx.z == 1) ? W1 : W2;
    unsigned short* Wt = (blockIdx.z == 0) ? T0 : (blockIdx.z == 1) ? T1 : T2;
    __shared__ __align__(16) unsigned short Ls[64 * 72];
    const int t = threadIdx.x;
    const int k0 = blockIdx.y * 64, n0 = blockIdx.x * 64;
    const int r = t >> 4, c4 = (t & 15) * 4;
    #pragma unroll
    for (int i = 0; i < 4; ++i) {
        float4 wv = *(const float4*)&W[(size_t)(k0 + r + i * 16) * 1024 + n0 + c4];
        Ls[(c4 + 0) * 72 + r + i * 16] = f2bf(wv.x);
        Ls[(c4 + 1) * 72 + r + i * 16] = f2bf(wv.y);
        Ls[(c4 + 2) * 72 + r + i * 16] = f2bf(wv.z);
        Ls[(c4 + 3) * 72 + r + i * 16] = f2bf(wv.w);
    }
    __syncthreads();
    #pragma unroll
    for (int i = 0; i < 2; ++i) {
        const int p = i * 256 + t;
        const int n = p & 63, kc = p >> 6;
        s16x8 v = *(const s16x8*)&Ls[n * 72 + kc * 8];
        const int gn = n0 + n, k = k0 + kc * 8;
        const size_t g = ((size_t)(gn >> 7) * 128 + (k >> 3)) * 128 + (gn & 127);
        *(s16x8*)&Wt[g * 8] = v;
    }
}

// A[4096][1024] fp32 -> bf16 A/W swizzle (no transpose). Grid (16 k-tiles, 32 rp, 3 z).
__global__ __launch_bounds__(256)
void cvtA(const float* __restrict__ A0, const float* __restrict__ A1, const float* __restrict__ A2,
          unsigned short* __restrict__ O0, unsigned short* __restrict__ O1, unsigned short* __restrict__ O2) {
    const float* A = (blockIdx.z == 0) ? A0 : (blockIdx.z == 1) ? A1 : A2;
    unsigned short* O = (blockIdx.z == 0) ? O0 : (blockIdx.z == 1) ? O1 : O2;
    __shared__ __align__(16) unsigned short Ls[8192];   // 16 KB
    const int t = threadIdx.x;
    const int k0 = blockIdx.x * 64, rp = blockIdx.y;
    const int row = t >> 1, kh = (t & 1) * 32;
    const float* src = A + (size_t)(rp * 128 + row) * 1024 + k0 + kh;
    float4 f[8];
    #pragma unroll
    for (int i = 0; i < 8; ++i) f[i] = ((const float4*)src)[i];
    #pragma unroll
    for (int j = 0; j < 4; ++j) {
        uint4 u;
        u.x = pkbf(f[j * 2].x, f[j * 2].y);
        u.y = pkbf(f[j * 2].z, f[j * 2].w);
        u.z = pkbf(f[j * 2 + 1].x, f[j * 2 + 1].y);
        u.w = pkbf(f[j * 2 + 1].z, f[j * 2 + 1].w);
        const int kc = (t & 1) * 4 + j;
        *(uint4*)&Ls[(kc * 128 + row) * 8] = u;
    }
    __syncthreads();
    const size_t gbase = ((size_t)rp * 128 + (k0 >> 3)) * 128;
    #pragma unroll
    for (int i = 0; i < 4; ++i) {
        const int idx = i * 256 + t;
        *(uint4*)&O[(gbase + idx) * 8] = *(const uint4*)&Ls[idx * 8];
    }
}

// QKV GEMM: C = A_bf16 @ W^T, both operands DMA. 128x128 tile, BK=32, 32KB LDS,
// 3 blocks/CU, grid 768 = one round, XCD chunk 96, 2-buffer counted vmcnt(4).
__global__ __launch_bounds__(256, 3)
void gemm_qkv(const unsigned short* __restrict__ Aq, const unsigned short* __restrict__ Ak,
              const unsigned short* __restrict__ Av,
              const unsigned short* __restrict__ W0, const unsigned short* __restrict__ W1,
              const unsigned short* __restrict__ W2,
              unsigned short* __restrict__ OQ, unsigned short* __restrict__ OK,
              unsigned short* __restrict__ OV, float scaleQ) {
    const int p = blockIdx.x;
    const int L = (p & 7) * 96 + (p >> 3);          // 768 = 8 XCD x 96
    const int z = L >> 8;
    const int rem = L & 255;
    const int m0 = (rem >> 3) * 128, n0 = (rem & 7) * 128;
    const unsigned short* Asw = (z == 0) ? Aq : (z == 1) ? Ak : Av;
    const unsigned short* Bsw = (z == 0) ? W0 : (z == 1) ? W1 : W2;
    const float scale = (z == 0) ? scaleQ : 1.0f;

    __shared__ __align__(16) unsigned short Al[2][4096];
    __shared__ __align__(16) unsigned short Bl[2][4096];
    const int t = threadIdx.x, lane = t & 63, w = t >> 6;
    const int ln = lane & 15, qd = lane >> 4;
    const int mw = (w & 1) * 64, nw = (w >> 1) * 64;
    const size_t gaB = (size_t)(m0 >> 7) * 16384;
    const size_t gbB = (size_t)(n0 >> 7) * 16384;

    f32x4v acc[4][4] = {};

    auto stage = [&](int kt, int b) {
        const size_t ga = gaB + (size_t)kt * 512;
        const size_t gb = gbB + (size_t)kt * 512;
        #pragma unroll
        for (int j = 0; j < 2; ++j)
            gld_lds16(Asw + (ga + j * 256 + t) * 8, &Al[b][(j * 256 + w * 64) * 8]);
        #pragma unroll
        for (int j = 0; j < 2; ++j)
            gld_lds16(Bsw + (gb + j * 256 + t) * 8, &Bl[b][(j * 256 + w * 64) * 8]);
    };

    stage(0, 0);
    stage(1, 1);
    for (int kt = 0; kt < 32; ++kt) {
        if (kt < 31) asm volatile("s_waitcnt vmcnt(4)" ::: "memory");
        else         asm volatile("s_waitcnt vmcnt(0)" ::: "memory");
        __builtin_amdgcn_s_barrier();
        asm volatile("" ::: "memory");
        const int b = kt & 1;
        {
            s16x8 a[4], bb[4];
            #pragma unroll
            for (int mt = 0; mt < 4; ++mt)
                a[mt] = *(const s16x8*)&Al[b][(qd * 128 + mw + mt * 16 + ln) * 8];
            #pragma unroll
            for (int nt = 0; nt < 4; ++nt)
                bb[nt] = *(const s16x8*)&Bl[b][(qd * 128 + nw + nt * 16 + ln) * 8];
            #pragma unroll
            for (int mt = 0; mt < 4; ++mt)
                #pragma unroll
                for (int nt = 0; nt < 4; ++nt)
                    acc[mt][nt] = __builtin_amdgcn_mfma_f32_16x16x32_bf16(a[mt], bb[nt], acc[mt][nt], 0, 0, 0);
        }
        if (kt < 30) {
            __builtin_amdgcn_s_barrier();      // all waves done reading buf b
            asm volatile("" ::: "memory");
            stage(kt + 2, b);
        }
    }

    #pragma unroll
    for (int mt = 0; mt < 4; ++mt)
        #pragma unroll
        for (int nt = 0; nt < 4; ++nt)
            #pragma unroll
            for (int i = 0; i < 4; ++i) {
                const int m = m0 + mw + mt * 16 + qd * 4 + i;
                const int n = n0 + nw + nt * 16 + ln;
                const float v = acc[mt][nt][i] * scale;
                const int bh = (m >> 11) * 16 + (n >> 6), s = m & 2047, hd = n & 63;
                if (z == 0) {
                    OQ[((size_t)bh * 2048 + s) * 64 + hd] = f2bf(v);
                } else if (z == 1) {
                    const size_t g = ((size_t)(bh * 32 + (s >> 6)) * 8 + (hd >> 3)) * 64 + (s & 63);
                    OK[g * 8 + (hd & 7)] = f2bf(v);
                } else {
                    const size_t g = ((size_t)(bh * 32 + (s >> 6)) * 8 + ((s >> 3) & 7)) * 64 + hd;
                    OV[g * 8 + (s & 7)] = f2bf(v);
                }
            }
}

// Output GEMM: out = ctx_sw @ Wot^T. 128x64 tile, BK=64, 2-buffer counted vmcnt(6),
// raw s_barrier. 48KB LDS @ 2 blocks/CU; grid 512 = one round. XCD chunk 64.
__global__ __launch_bounds__(256, 2)
void gemm_out(const unsigned short* __restrict__ Asw, const unsigned short* __restrict__ Bsw,
              float* __restrict__ outF) {
    const int p = blockIdx.x;
    const int L = (p & 7) * 64 + (p >> 3);          // 512 = 8 XCD x 64
    const int m0 = (L >> 4) * 128, n0 = (L & 15) * 64;

    __shared__ __align__(16) unsigned short Al[2][8192];
    __shared__ __align__(16) unsigned short Bl[2][4096];
    const int t = threadIdx.x, lane = t & 63, w = t >> 6;
    const int ln = lane & 15, qd = lane >> 4;
    const int mw = (w & 1) * 64, nw = (w >> 1) * 32;
    const size_t gaB = (size_t)(m0 >> 7) * 16384;
    const size_t gbB = (size_t)(n0 >> 7) * 16384 + (n0 & 127);

    f32x4v acc[4][2] = {};

    auto stage = [&](int kt, int b) {
        const size_t ga = gaB + (size_t)kt * 1024;
        #pragma unroll
        for (int j = 0; j < 4; ++j)
            gld_lds16(Asw + (ga + j * 256 + t) * 8, &Al[b][(j * 256 + w * 64) * 8]);
        #pragma unroll
        for (int i = 0; i < 2; ++i) {
            const int c = w * 2 + i;
            const size_t gb = gbB + (size_t)(kt * 8 + c) * 128 + lane;
            gld_lds16(Bsw + gb * 8, &Bl[b][(c * 64) * 8]);
        }
    };

    stage(0, 0);
    stage(1, 1);
    for (int kt = 0; kt < 16; ++kt) {
        if (kt < 15) asm volatile("s_waitcnt vmcnt(6)" ::: "memory");
        else         asm volatile("s_waitcnt vmcnt(0)" ::: "memory");
        __builtin_amdgcn_s_barrier();
        asm volatile("" ::: "memory");
        const int b = kt & 1;
        #pragma unroll
        for (int kk = 0; kk < 2; ++kk) {
            const int kc = kk * 4 + qd;
            s16x8 a[4], bb[2];
            #pragma unroll
            for (int mt = 0; mt < 4; ++mt)
                a[mt] = *(const s16x8*)&Al[b][(kc * 128 + mw + mt * 16 + ln) * 8];
            #pragma unroll
            for (int nt = 0; nt < 2; ++nt)
                bb[nt] = *(const s16x8*)&Bl[b][(kc * 64 + nw + nt * 16 + ln) * 8];
            #pragma unroll
            for (int mt = 0; mt < 4; ++mt)
                #pragma unroll
                for (int nt = 0; nt < 2; ++nt)
                    acc[mt][nt] = __builtin_amdgcn_mfma_f32_16x16x32_bf16(a[mt], bb[nt], acc[mt][nt], 0, 0, 0);
        }
        if (kt < 14) {
            __builtin_amdgcn_s_barrier();
            asm volatile("" ::: "memory");
            stage(kt + 2, b);
        }
    }

    #pragma unroll
    for (int mt = 0; mt < 4; ++mt)
        #pragma unroll
        for (int nt = 0; nt < 2; ++nt)
            #pragma unroll
            for (int i = 0; i < 4; ++i) {
                const int m = m0 + mw + mt * 16 + qd * 4 + i;
                const int n = n0 + nw + nt * 16 + ln;
                outF[(size_t)m * 1024 + n] = acc[mt][nt][i];
            }
}

// Flash attention (KV-split=2): per tile, S^T = K Q^T (swapped), P = 2^S (exp2f —
// FROZEN, see R19/R20 header note), cvt_pk+permlane P-frags, rowsum via MFMA ones-B
// (accL[r] = rowsum(q=crow(r,H)) at the exact (lane,reg) the epilogue needs).
__device__ __forceinline__ void fa_compute(
        const unsigned short* Ksb, const unsigned short* Vsb,
        const int H, const int l31, const s16x8* qf,
        f32x16v* accO, f32x16v& accL) {
    f32x16v accS[2] = {};
    #pragma unroll
    for (int kk = 0; kk < 4; ++kk) {
        s16x8 kf0 = *(const s16x8*)&Ksb[((kk * 2 + H) * 64 + l31) * 8];
        s16x8 kf1 = *(const s16x8*)&Ksb[((kk * 2 + H) * 64 + 32 + l31) * 8];
        accS[0] = __builtin_amdgcn_mfma_f32_32x32x16_bf16(kf0, qf[kk], accS[0], 0, 0, 0);
        accS[1] = __builtin_amdgcn_mfma_f32_32x32x16_bf16(kf1, qf[kk], accS[1], 0, 0, 0);
    }

    u32x4v af[4];
    #pragma unroll
    for (int mt = 0; mt < 2; ++mt) {
        float p[16];
        #pragma unroll
        for (int r = 0; r < 16; ++r)
            p[r] = exp2f(accS[mt][r]);
        unsigned int C[8];
        #pragma unroll
        for (int j = 0; j < 8; ++j)
            asm("v_cvt_pk_bf16_f32 %0, %1, %2" : "=v"(C[j]) : "v"(p[2 * j]), "v"(p[2 * j + 1]));
        #pragma unroll
        for (int pp = 0; pp < 2; ++pp) {
            unsigned int x0 = C[4 * pp + 0], y0 = C[4 * pp + 2];
            unsigned int x1 = C[4 * pp + 1], y1 = C[4 * pp + 3];
            asm("v_permlane32_swap_b32 %0, %1" : "+v"(x0), "+v"(y0));
            asm("v_permlane32_swap_b32 %0, %1" : "+v"(x1), "+v"(y1));
            u32x4v a; a.x = x0; a.y = x1; a.z = y0; a.w = y1;
            af[mt * 2 + pp] = a;
        }
    }

    const s16x8 ones = {(short)0x3F80, (short)0x3F80, (short)0x3F80, (short)0x3F80,
                        (short)0x3F80, (short)0x3F80, (short)0x3F80, (short)0x3F80};
    #pragma unroll
    for (int kk2 = 0; kk2 < 4; ++kk2) {
        s16x8 a = __builtin_bit_cast(s16x8, af[kk2]);
        s16x8 vf0 = *(const s16x8*)&Vsb[((kk2 * 2 + H) * 64 + l31) * 8];
        s16x8 vf1 = *(const s16x8*)&Vsb[((kk2 * 2 + H) * 64 + 32 + l31) * 8];
        accO[0] = __builtin_amdgcn_mfma_f32_32x32x16_bf16(a, vf0, accO[0], 0, 0, 0);
        accO[1] = __builtin_amdgcn_mfma_f32_32x32x16_bf16(a, vf1, accO[1], 0, 0, 0);
        accL    = __builtin_amdgcn_mfma_f32_32x32x16_bf16(a, ones, accL, 0, 0, 0);
    }
}

// Grid 1024 = 8 XCD x 128 (4 heads/XCD). Each block: 128 q-rows x 16 kt tiles
// (half the KV range). 2-buffer 32KB LDS, two-barrier counted vmcnt(4), 4 blocks/CU.
__global__ __launch_bounds__(256, 4)
void fattn_sp(const unsigned short* __restrict__ Q, const unsigned short* __restrict__ Ksw,
              const unsigned short* __restrict__ Vsw, unsigned short* __restrict__ Opart,
              float* __restrict__ Lpart) {
    __shared__ __align__(16) unsigned short Ks2[2][4096];
    __shared__ __align__(16) unsigned short Vs2[2][4096];

    const int t = threadIdx.x, lane = t & 63, w = t >> 6;
    const int l31 = lane & 31, H = lane >> 5;
    const int bid = blockIdx.x;
    const int wid = (bid & 7) * 128 + (bid >> 3);   // 1024 = 8 XCD x 128
    const int bh = wid >> 5, inner = wid & 31;
    const int split = inner >> 4, mblk = inner & 15;
    const int m0 = mblk * 128;
    const size_t head = (size_t)bh * 2048 * 64;

    s16x8 qf[4];
    #pragma unroll
    for (int kk = 0; kk < 4; ++kk)
        qf[kk] = *(const s16x8*)(Q + head + (size_t)(m0 + w * 32 + l31) * 64 + kk * 16 + H * 8);
    asm volatile("s_waitcnt vmcnt(0)" ::: "memory");
    #pragma unroll
    for (int kk = 0; kk < 4; ++kk) {
        u32x4v q = __builtin_bit_cast(u32x4v, qf[kk]);
        asm volatile("" : "+v"(q.x), "+v"(q.y), "+v"(q.z), "+v"(q.w));
        qf[kk] = __builtin_bit_cast(s16x8, q);
    }

    const size_t tb = (size_t)(bh * 32 + split * 16) * 512;
    auto stage = [&](int kt, int b) {   // 4 vm-ops per wave
        const size_t tk = tb + (size_t)kt * 512;
        #pragma unroll
        for (int j = 0; j < 2; ++j)
            gld_lds16(Ksw + (tk + j * 256 + t) * 8, &Ks2[b][(j * 256 + w * 64) * 8]);
        #pragma unroll
        for (int j = 0; j < 2; ++j)
            gld_lds16(Vsw + (tk + j * 256 + t) * 8, &Vs2[b][(j * 256 + w * 64) * 8]);
    };

    stage(0, 0);
    stage(1, 1);

    f32x16v accO[2] = {};
    f32x16v accL = {};

    for (int kt = 0; kt < 16; ++kt) {
        if (kt < 15) asm volatile("s_waitcnt vmcnt(4)" ::: "memory");
        else         asm volatile("s_waitcnt vmcnt(0)" ::: "memory");
        __builtin_amdgcn_s_barrier();
        asm volatile("" ::: "memory");
        fa_compute(Ks2[kt & 1], Vs2[kt & 1], H, l31, qf, accO, accL);
        if (kt < 14) {
            __builtin_amdgcn_s_barrier();   // all waves done reading buf kt&1
            asm volatile("" ::: "memory");
            stage(kt + 2, kt & 1);
        }
    }

    // dump partials: accO as bf16 (per-thread 64B), accL f32 (per (w,H), lanes l31==0)
    const int lb = bh * 16 + mblk;
    unsigned int Wd[16];
    #pragma unroll
    for (int nt = 0; nt < 2; ++nt)
        #pragma unroll
        for (int r = 0; r < 16; r += 2)
            Wd[nt * 8 + r / 2] = pkbf(accO[nt][r], accO[nt][r + 1]);
    uint4* od = (uint4*)(Opart + ((size_t)(split * 512 + lb) * 256 + t) * 32);
    od[0] = *(const uint4*)&Wd[0];
    od[1] = *(const uint4*)&Wd[4];
    od[2] = *(const uint4*)&Wd[8];
    od[3] = *(const uint4*)&Wd[12];
    if (l31 == 0) {
        float lv[16];
        #pragma unroll
        for (int r = 0; r < 16; ++r) lv[r] = accL[r];
        float4* ld = (float4*)(Lpart + (((size_t)(split * 512 + lb) * 4 + w) * 2 + H) * 16);
        ld[0] = *(const float4*)&lv[0];
        ld[1] = *(const float4*)&lv[4];
        ld[2] = *(const float4*)&lv[8];
        ld[3] = *(const float4*)&lv[12];
    }
}

// Combine: ctx = (O0 + O1) / (L0 + L1), written in A/W swizzle. Grid 512 x 256.
__global__ __launch_bounds__(256)
void fa_comb(const unsigned short* __restrict__ Opart, const float* __restrict__ Lpart,
             unsigned short* __restrict__ ctx) {
    const int lb = blockIdx.x, t = threadIdx.x;
    const int lane = t & 63, w = t >> 6;
    const int l31 = lane & 31, H = lane >> 5;
    const int bh = lb >> 4, m0 = (lb & 15) * 128;

    const float* L0 = Lpart + (((size_t)lb * 4 + w) * 2 + H) * 16;
    const float* L1 = Lpart + (((size_t)(512 + lb) * 4 + w) * 2 + H) * 16;
    float inv[16];
    #pragma unroll
    for (int r = 0; r < 16; ++r) inv[r] = 1.f / (L0[r] + L1[r]);

    const uint4* o0 = (const uint4*)(Opart + ((size_t)lb * 256 + t) * 32);
    const uint4* o1 = (const uint4*)(Opart + ((size_t)(512 + lb) * 256 + t) * 32);
    unsigned int A0[16], A1[16];
    *(uint4*)&A0[0] = o0[0]; *(uint4*)&A0[4] = o0[1];
    *(uint4*)&A0[8] = o0[2]; *(uint4*)&A0[12] = o0[3];
    *(uint4*)&A1[0] = o1[0]; *(uint4*)&A1[4] = o1[1];
    *(uint4*)&A1[8] = o1[2]; *(uint4*)&A1[12] = o1[3];

    #pragma unroll
    for (int r = 0; r < 16; ++r) {
        const int qloc = (r & 3) + 8 * (r >> 2) + 4 * H;
        const int mrow = (bh >> 4) * 2048 + m0 + w * 32 + qloc;
        #pragma unroll
        for (int nt = 0; nt < 2; ++nt) {
            const int j = nt * 16 + r;
            const unsigned int w0 = A0[j >> 1], w1 = A1[j >> 1];
            const unsigned short h0 = (j & 1) ? (unsigned short)(w0 >> 16) : (unsigned short)(w0 & 0xFFFF);
            const unsigned short h1 = (j & 1) ? (unsigned short)(w1 >> 16) : (unsigned short)(w1 & 0xFFFF);
            const float out = (bf2f(h0) + bf2f(h1)) * inv[r];
            const int k = (bh & 15) * 64 + nt * 32 + l31;
            const size_t g = ((size_t)(mrow >> 7) * 128 + (k >> 3)) * 128 + (mrow & 127);
            ctx[g * 8 + (k & 7)] = f2bf(out);
        }
    }
}

extern "C" void kernel_launch(void* const* d_in, const int* in_sizes, int n_in,
                              void* d_out, int out_size, void* d_ws, size_t ws_size,
                              hipStream_t stream) {
    char* ws = (char*)d_ws;
    unsigned short* Qb    = (unsigned short*)(ws);
    unsigned short* Ksw   = (unsigned short*)(ws + ((size_t)8 << 20));
    unsigned short* Vsw   = (unsigned short*)(ws + ((size_t)16 << 20));
    unsigned short* Wqt   = (unsigned short*)(ws + ((size_t)24 << 20));
    unsigned short* Wkt   = (unsigned short*)(ws + ((size_t)26 << 20));
    unsigned short* Wvt   = (unsigned short*)(ws + ((size_t)28 << 20));
    unsigned short* Aq    = (unsigned short*)(ws + ((size_t)30 << 20));
    unsigned short* Ak    = (unsigned short*)(ws + ((size_t)38 << 20));
    unsigned short* Av    = (unsigned short*)(ws + ((size_t)46 << 20));
    unsigned short* ctx   = (unsigned short*)(ws + ((size_t)24 << 20));  // after QKV GEMM
    unsigned short* Opart = (unsigned short*)(ws + ((size_t)32 << 20));  // overlays dead Aq/Ak
    float*          Lpart = (float*)         (ws + ((size_t)48 << 20));  // overlays dead Av
    unsigned short* Wot   = (unsigned short*)(ws);                        // [0,2): Qb dead after fattn_sp

    cvt3<<<dim3(16, 16, 3), 256, 0, stream>>>((const float*)d_in[3], (const float*)d_in[4],
                                              (const float*)d_in[5], Wqt, Wkt, Wvt);

    cvtA<<<dim3(16, 32, 3), 256, 0, stream>>>((const float*)d_in[0], (const float*)d_in[1],
                                              (const float*)d_in[2], Aq, Ak, Av);
    gemm_qkv<<<dim3(768), 256, 0, stream>>>(Aq, Ak, Av, Wqt, Wkt, Wvt,
                                            Qb, Ksw, Vsw, 0.125f * 1.44269504f);

    fattn_sp<<<dim3(1024), 256, 0, stream>>>(Qb, Ksw, Vsw, Opart, Lpart);

    cvt3<<<dim3(16, 16, 1), 256, 0, stream>>>((const float*)d_in[6], nullptr, nullptr,
                                              Wot, nullptr, nullptr);

    fa_comb<<<dim3(512), 256, 0, stream>>>(Opart, Lpart, ctx);

    gemm_out<<<dim3(512), 256, 0, stream>>>(ctx, Wot, (float*)d_out);
}

// Round 14
// 221.897 us; speedup vs baseline: 1.0293x; 1.0023x over previous
//
#include <hip/hip_runtime.h>
#include <hip/hip_bf16.h>

// MHA: B=2, S=2048, D=1024, H=16, HD=64. fp32 in, fp32 out.
// Swizzled bf16 inter-kernel layouts (16B blocks) so all staging is contiguous DMA:
//   A/W swizzle ([R][K=1024]): block g=((r>>7)*128+(k>>3))*128+(r&127)
//   K_sw/V_sw: block g=((bh*32+kt)*8+kc)*64+row
// ws (>=54MB proven): [0,8)MB Qb | [8,16) Ksw | [16,24) Vsw | [24,30) Wq/k/vt |
//   [30,38) Aq | [38,46) Ak | [46,54) Av. ctx overlays [24,32) after QKV GEMM;
//   Opart [32,48) + Lpart [48,48.5) overlay dead Aq/Ak/Av during fattn;
//   Wot at [0,2) written AFTER fattn_sp (Qb dead) by comb_wo's cvt blocks.
// Q-proj scale folds 1/sqrt(HD)*log2(e) so fattn uses native exp2 range.
// R9-R13: fattn ladder 75->65us. R14: DMA GEMMs 241->233. R15/16: KV-split+ones-B
//   rowsum 225.7. R17/18: 3-buf single-barrier gemms neutral; Wot overlay bug
//   (lesson: check overlays against ALL later writers). R19/R20: raw v_exp_f32
//   (asm AND builtin) both FAIL absmax ~0.05 — likely TRANS->inline-asm-consumer
//   hazard the recognizer can't see; OCML's guard ops provide the wait states.
//   exp2f FROZEN. R21: revert to R16 config = 222.4us BEST.
// R22 (this): launch-count 7->5 (est. ~80us of inter-kernel gaps in the budget):
//   prep6 = cvt3(Wq,Wk,Wv) + cvtA merged via blockIdx.z (Wo NOT included - R17
//   lesson); comb_wo = fa_comb + cvt3(Wo) merged via blockIdx.x split. All compute
//   kernels byte-identical to R21 (frozen controls).

typedef short s16x8 __attribute__((ext_vector_type(8)));
typedef float f32x4v __attribute__((ext_vector_type(4)));
typedef float f32x16v __attribute__((ext_vector_type(16)));
typedef unsigned int u32x4v __attribute__((ext_vector_type(4)));

__device__ inline unsigned short f2bf(float f) {   // RNE (proven R2-R6)
    union { float f; unsigned int i; } x; x.f = f;
    unsigned int r = x.i + 0x7FFFu + ((x.i >> 16) & 1u);
    return (unsigned short)(r >> 16);
}
__device__ inline unsigned int pkbf(float lo, float hi) {  // lo16=bf(lo), hi16=bf(hi)
    return (unsigned int)f2bf(lo) | ((unsigned int)f2bf(hi) << 16);
}
__device__ inline float bf2f(unsigned short u) {
    union { unsigned int i; float f; } x; x.i = (unsigned int)u << 16; return x.f;
}

// async global->LDS, 16B/lane. Global address PER-LANE; LDS base wave-uniform,
// HW writes base + lane*16.
__device__ inline void gld_lds16(const unsigned short* g, unsigned short* l) {
    __builtin_amdgcn_global_load_lds(
        (const __attribute__((address_space(1))) unsigned int*)(const void*)g,
        (__attribute__((address_space(3))) unsigned int*)(void*)l,
        16, 0, 0);
}

// W[K=1024][N=1024] fp32 tile -> bf16 A/W swizzle (transpose+convert), one 64x64 tile.
__device__ __forceinline__ void cvtW_tile(const float* __restrict__ W,
                                          unsigned short* __restrict__ Wt,
                                          unsigned short* Ls, int k0, int n0, int t) {
    const int r = t >> 4, c4 = (t & 15) * 4;
    #pragma unroll
    for (int i = 0; i < 4; ++i) {
        float4 wv = *(const float4*)&W[(size_t)(k0 + r + i * 16) * 1024 + n0 + c4];
        Ls[(c4 + 0) * 72 + r + i * 16] = f2bf(wv.x);
        Ls[(c4 + 1) * 72 + r + i * 16] = f2bf(wv.y);
        Ls[(c4 + 2) * 72 + r + i * 16] = f2bf(wv.z);
        Ls[(c4 + 3) * 72 + r + i * 16] = f2bf(wv.w);
    }
    __syncthreads();
    #pragma unroll
    for (int i = 0; i < 2; ++i) {
        const int p = i * 256 + t;
        const int n = p & 63, kc = p >> 6;
        s16x8 v = *(const s16x8*)&Ls[n * 72 + kc * 8];
        const int gn = n0 + n, k = k0 + kc * 8;
        const size_t g = ((size_t)(gn >> 7) * 128 + (k >> 3)) * 128 + (gn & 127);
        *(s16x8*)&Wt[g * 8] = v;
    }
}

// prep6 (R22): z<3 -> cvtA (A[4096][1024] fp32 -> bf16 A/W swizzle, grid y in [0,32));
//              z>=3 -> cvt3 (W fp32 -> bf16 swizzle, grid y in [0,16), y>=16 exits).
// Wo is NOT here: cvtA's Av write [46,54) runs in this same kernel (R17 lesson).
__global__ __launch_bounds__(256)
void prep6(const float* __restrict__ A0, const float* __restrict__ A1, const float* __restrict__ A2,
           const float* __restrict__ W0, const float* __restrict__ W1, const float* __restrict__ W2,
           unsigned short* __restrict__ OA0, unsigned short* __restrict__ OA1, unsigned short* __restrict__ OA2,
           unsigned short* __restrict__ OW0, unsigned short* __restrict__ OW1, unsigned short* __restrict__ OW2) {
    __shared__ __align__(16) unsigned short Ls[8192];   // 16 KB (max of both bodies)
    const int z = blockIdx.z, t = threadIdx.x;
    if (z < 3) {
        const float* A = (z == 0) ? A0 : (z == 1) ? A1 : A2;
        unsigned short* O = (z == 0) ? OA0 : (z == 1) ? OA1 : OA2;
        const int k0 = blockIdx.x * 64, rp = blockIdx.y;
        const int row = t >> 1, kh = (t & 1) * 32;
        const float* src = A + (size_t)(rp * 128 + row) * 1024 + k0 + kh;
        float4 f[8];
        #pragma unroll
        for (int i = 0; i < 8; ++i) f[i] = ((const float4*)src)[i];
        #pragma unroll
        for (int j = 0; j < 4; ++j) {
            uint4 u;
            u.x = pkbf(f[j * 2].x, f[j * 2].y);
            u.y = pkbf(f[j * 2].z, f[j * 2].w);
            u.z = pkbf(f[j * 2 + 1].x, f[j * 2 + 1].y);
            u.w = pkbf(f[j * 2 + 1].z, f[j * 2 + 1].w);
            const int kc = (t & 1) * 4 + j;
            *(uint4*)&Ls[(kc * 128 + row) * 8] = u;
        }
        __syncthreads();
        const size_t gbase = ((size_t)rp * 128 + (k0 >> 3)) * 128;
        #pragma unroll
        for (int i = 0; i < 4; ++i) {
            const int idx = i * 256 + t;
            *(uint4*)&O[(gbase + idx) * 8] = *(const uint4*)&Ls[idx * 8];
        }
    } else {
        if (blockIdx.y >= 16) return;
        const int zi = z - 3;
        const float* W = (zi == 0) ? W0 : (zi == 1) ? W1 : W2;
        unsigned short* Wt = (zi == 0) ? OW0 : (zi == 1) ? OW1 : OW2;
        cvtW_tile(W, Wt, Ls, blockIdx.y * 64, blockIdx.x * 64, t);
    }
}

// QKV GEMM: C = A_bf16 @ W^T, both operands DMA. 128x128 tile, BK=32, 32KB LDS,
// 3 blocks/CU, grid 768 = one round, XCD chunk 96, 2-buffer counted vmcnt(4).
__global__ __launch_bounds__(256, 3)
void gemm_qkv(const unsigned short* __restrict__ Aq, const unsigned short* __restrict__ Ak,
              const unsigned short* __restrict__ Av,
              const unsigned short* __restrict__ W0, const unsigned short* __restrict__ W1,
              const unsigned short* __restrict__ W2,
              unsigned short* __restrict__ OQ, unsigned short* __restrict__ OK,
              unsigned short* __restrict__ OV, float scaleQ) {
    const int p = blockIdx.x;
    const int L = (p & 7) * 96 + (p >> 3);          // 768 = 8 XCD x 96
    const int z = L >> 8;
    const int rem = L & 255;
    const int m0 = (rem >> 3) * 128, n0 = (rem & 7) * 128;
    const unsigned short* Asw = (z == 0) ? Aq : (z == 1) ? Ak : Av;
    const unsigned short* Bsw = (z == 0) ? W0 : (z == 1) ? W1 : W2;
    const float scale = (z == 0) ? scaleQ : 1.0f;

    __shared__ __align__(16) unsigned short Al[2][4096];
    __shared__ __align__(16) unsigned short Bl[2][4096];
    const int t = threadIdx.x, lane = t & 63, w = t >> 6;
    const int ln = lane & 15, qd = lane >> 4;
    const int mw = (w & 1) * 64, nw = (w >> 1) * 64;
    const size_t gaB = (size_t)(m0 >> 7) * 16384;
    const size_t gbB = (size_t)(n0 >> 7) * 16384;

    f32x4v acc[4][4] = {};

    auto stage = [&](int kt, int b) {
        const size_t ga = gaB + (size_t)kt * 512;
        const size_t gb = gbB + (size_t)kt * 512;
        #pragma unroll
        for (int j = 0; j < 2; ++j)
            gld_lds16(Asw + (ga + j * 256 + t) * 8, &Al[b][(j * 256 + w * 64) * 8]);
        #pragma unroll
        for (int j = 0; j < 2; ++j)
            gld_lds16(Bsw + (gb + j * 256 + t) * 8, &Bl[b][(j * 256 + w * 64) * 8]);
    };

    stage(0, 0);
    stage(1, 1);
    for (int kt = 0; kt < 32; ++kt) {
        if (kt < 31) asm volatile("s_waitcnt vmcnt(4)" ::: "memory");
        else         asm volatile("s_waitcnt vmcnt(0)" ::: "memory");
        __builtin_amdgcn_s_barrier();
        asm volatile("" ::: "memory");
        const int b = kt & 1;
        {
            s16x8 a[4], bb[4];
            #pragma unroll
            for (int mt = 0; mt < 4; ++mt)
                a[mt] = *(const s16x8*)&Al[b][(qd * 128 + mw + mt * 16 + ln) * 8];
            #pragma unroll
            for (int nt = 0; nt < 4; ++nt)
                bb[nt] = *(const s16x8*)&Bl[b][(qd * 128 + nw + nt * 16 + ln) * 8];
            #pragma unroll
            for (int mt = 0; mt < 4; ++mt)
                #pragma unroll
                for (int nt = 0; nt < 4; ++nt)
                    acc[mt][nt] = __builtin_amdgcn_mfma_f32_16x16x32_bf16(a[mt], bb[nt], acc[mt][nt], 0, 0, 0);
        }
        if (kt < 30) {
            __builtin_amdgcn_s_barrier();      // all waves done reading buf b
            asm volatile("" ::: "memory");
            stage(kt + 2, b);
        }
    }

    #pragma unroll
    for (int mt = 0; mt < 4; ++mt)
        #pragma unroll
        for (int nt = 0; nt < 4; ++nt)
            #pragma unroll
            for (int i = 0; i < 4; ++i) {
                const int m = m0 + mw + mt * 16 + qd * 4 + i;
                const int n = n0 + nw + nt * 16 + ln;
                const float v = acc[mt][nt][i] * scale;
                const int bh = (m >> 11) * 16 + (n >> 6), s = m & 2047, hd = n & 63;
                if (z == 0) {
                    OQ[((size_t)bh * 2048 + s) * 64 + hd] = f2bf(v);
                } else if (z == 1) {
                    const size_t g = ((size_t)(bh * 32 + (s >> 6)) * 8 + (hd >> 3)) * 64 + (s & 63);
                    OK[g * 8 + (hd & 7)] = f2bf(v);
                } else {
                    const size_t g = ((size_t)(bh * 32 + (s >> 6)) * 8 + ((s >> 3) & 7)) * 64 + hd;
                    OV[g * 8 + (s & 7)] = f2bf(v);
                }
            }
}

// Output GEMM: out = ctx_sw @ Wot^T. 128x64 tile, BK=64, 2-buffer counted vmcnt(6),
// raw s_barrier. 48KB LDS @ 2 blocks/CU; grid 512 = one round. XCD chunk 64.
__global__ __launch_bounds__(256, 2)
void gemm_out(const unsigned short* __restrict__ Asw, const unsigned short* __restrict__ Bsw,
              float* __restrict__ outF) {
    const int p = blockIdx.x;
    const int L = (p & 7) * 64 + (p >> 3);          // 512 = 8 XCD x 64
    const int m0 = (L >> 4) * 128, n0 = (L & 15) * 64;

    __shared__ __align__(16) unsigned short Al[2][8192];
    __shared__ __align__(16) unsigned short Bl[2][4096];
    const int t = threadIdx.x, lane = t & 63, w = t >> 6;
    const int ln = lane & 15, qd = lane >> 4;
    const int mw = (w & 1) * 64, nw = (w >> 1) * 32;
    const size_t gaB = (size_t)(m0 >> 7) * 16384;
    const size_t gbB = (size_t)(n0 >> 7) * 16384 + (n0 & 127);

    f32x4v acc[4][2] = {};

    auto stage = [&](int kt, int b) {
        const size_t ga = gaB + (size_t)kt * 1024;
        #pragma unroll
        for (int j = 0; j < 4; ++j)
            gld_lds16(Asw + (ga + j * 256 + t) * 8, &Al[b][(j * 256 + w * 64) * 8]);
        #pragma unroll
        for (int i = 0; i < 2; ++i) {
            const int c = w * 2 + i;
            const size_t gb = gbB + (size_t)(kt * 8 + c) * 128 + lane;
            gld_lds16(Bsw + gb * 8, &Bl[b][(c * 64) * 8]);
        }
    };

    stage(0, 0);
    stage(1, 1);
    for (int kt = 0; kt < 16; ++kt) {
        if (kt < 15) asm volatile("s_waitcnt vmcnt(6)" ::: "memory");
        else         asm volatile("s_waitcnt vmcnt(0)" ::: "memory");
        __builtin_amdgcn_s_barrier();
        asm volatile("" ::: "memory");
        const int b = kt & 1;
        #pragma unroll
        for (int kk = 0; kk < 2; ++kk) {
            const int kc = kk * 4 + qd;
            s16x8 a[4], bb[2];
            #pragma unroll
            for (int mt = 0; mt < 4; ++mt)
                a[mt] = *(const s16x8*)&Al[b][(kc * 128 + mw + mt * 16 + ln) * 8];
            #pragma unroll
            for (int nt = 0; nt < 2; ++nt)
                bb[nt] = *(const s16x8*)&Bl[b][(kc * 64 + nw + nt * 16 + ln) * 8];
            #pragma unroll
            for (int mt = 0; mt < 4; ++mt)
                #pragma unroll
                for (int nt = 0; nt < 2; ++nt)
                    acc[mt][nt] = __builtin_amdgcn_mfma_f32_16x16x32_bf16(a[mt], bb[nt], acc[mt][nt], 0, 0, 0);
        }
        if (kt < 14) {
            __builtin_amdgcn_s_barrier();
            asm volatile("" ::: "memory");
            stage(kt + 2, b);
        }
    }

    #pragma unroll
    for (int mt = 0; mt < 4; ++mt)
        #pragma unroll
        for (int nt = 0; nt < 2; ++nt)
            #pragma unroll
            for (int i = 0; i < 4; ++i) {
                const int m = m0 + mw + mt * 16 + qd * 4 + i;
                const int n = n0 + nw + nt * 16 + ln;
                outF[(size_t)m * 1024 + n] = acc[mt][nt][i];
            }
}

// Flash attention (KV-split=2): per tile, S^T = K Q^T (swapped), P = 2^S (exp2f —
// FROZEN, see R19/R20 header note), cvt_pk+permlane P-frags, rowsum via MFMA ones-B
// (accL[r] = rowsum(q=crow(r,H)) at the exact (lane,reg) the epilogue needs).
__device__ __forceinline__ void fa_compute(
        const unsigned short* Ksb, const unsigned short* Vsb,
        const int H, const int l31, const s16x8* qf,
        f32x16v* accO, f32x16v& accL) {
    f32x16v accS[2] = {};
    #pragma unroll
    for (int kk = 0; kk < 4; ++kk) {
        s16x8 kf0 = *(const s16x8*)&Ksb[((kk * 2 + H) * 64 + l31) * 8];
        s16x8 kf1 = *(const s16x8*)&Ksb[((kk * 2 + H) * 64 + 32 + l31) * 8];
        accS[0] = __builtin_amdgcn_mfma_f32_32x32x16_bf16(kf0, qf[kk], accS[0], 0, 0, 0);
        accS[1] = __builtin_amdgcn_mfma_f32_32x32x16_bf16(kf1, qf[kk], accS[1], 0, 0, 0);
    }

    u32x4v af[4];
    #pragma unroll
    for (int mt = 0; mt < 2; ++mt) {
        float p[16];
        #pragma unroll
        for (int r = 0; r < 16; ++r)
            p[r] = exp2f(accS[mt][r]);
        unsigned int C[8];
        #pragma unroll
        for (int j = 0; j < 8; ++j)
            asm("v_cvt_pk_bf16_f32 %0, %1, %2" : "=v"(C[j]) : "v"(p[2 * j]), "v"(p[2 * j + 1]));
        #pragma unroll
        for (int pp = 0; pp < 2; ++pp) {
            unsigned int x0 = C[4 * pp + 0], y0 = C[4 * pp + 2];
            unsigned int x1 = C[4 * pp + 1], y1 = C[4 * pp + 3];
            asm("v_permlane32_swap_b32 %0, %1" : "+v"(x0), "+v"(y0));
            asm("v_permlane32_swap_b32 %0, %1" : "+v"(x1), "+v"(y1));
            u32x4v a; a.x = x0; a.y = x1; a.z = y0; a.w = y1;
            af[mt * 2 + pp] = a;
        }
    }

    const s16x8 ones = {(short)0x3F80, (short)0x3F80, (short)0x3F80, (short)0x3F80,
                        (short)0x3F80, (short)0x3F80, (short)0x3F80, (short)0x3F80};
    #pragma unroll
    for (int kk2 = 0; kk2 < 4; ++kk2) {
        s16x8 a = __builtin_bit_cast(s16x8, af[kk2]);
        s16x8 vf0 = *(const s16x8*)&Vsb[((kk2 * 2 + H) * 64 + l31) * 8];
        s16x8 vf1 = *(const s16x8*)&Vsb[((kk2 * 2 + H) * 64 + 32 + l31) * 8];
        accO[0] = __builtin_amdgcn_mfma_f32_32x32x16_bf16(a, vf0, accO[0], 0, 0, 0);
        accO[1] = __builtin_amdgcn_mfma_f32_32x32x16_bf16(a, vf1, accO[1], 0, 0, 0);
        accL    = __builtin_amdgcn_mfma_f32_32x32x16_bf16(a, ones, accL, 0, 0, 0);
    }
}

// Grid 1024 = 8 XCD x 128 (4 heads/XCD). Each block: 128 q-rows x 16 kt tiles
// (half the KV range). 2-buffer 32KB LDS, two-barrier counted vmcnt(4), 4 blocks/CU.
__global__ __launch_bounds__(256, 4)
void fattn_sp(const unsigned short* __restrict__ Q, const unsigned short* __restrict__ Ksw,
              const unsigned short* __restrict__ Vsw, unsigned short* __restrict__ Opart,
              float* __restrict__ Lpart) {
    __shared__ __align__(16) unsigned short Ks2[2][4096];
    __shared__ __align__(16) unsigned short Vs2[2][4096];

    const int t = threadIdx.x, lane = t & 63, w = t >> 6;
    const int l31 = lane & 31, H = lane >> 5;
    const int bid = blockIdx.x;
    const int wid = (bid & 7) * 128 + (bid >> 3);   // 1024 = 8 XCD x 128
    const int bh = wid >> 5, inner = wid & 31;
    const int split = inner >> 4, mblk = inner & 15;
    const int m0 = mblk * 128;
    const size_t head = (size_t)bh * 2048 * 64;

    s16x8 qf[4];
    #pragma unroll
    for (int kk = 0; kk < 4; ++kk)
        qf[kk] = *(const s16x8*)(Q + head + (size_t)(m0 + w * 32 + l31) * 64 + kk * 16 + H * 8);
    asm volatile("s_waitcnt vmcnt(0)" ::: "memory");
    #pragma unroll
    for (int kk = 0; kk < 4; ++kk) {
        u32x4v q = __builtin_bit_cast(u32x4v, qf[kk]);
        asm volatile("" : "+v"(q.x), "+v"(q.y), "+v"(q.z), "+v"(q.w));
        qf[kk] = __builtin_bit_cast(s16x8, q);
    }

    const size_t tb = (size_t)(bh * 32 + split * 16) * 512;
    auto stage = [&](int kt, int b) {   // 4 vm-ops per wave
        const size_t tk = tb + (size_t)kt * 512;
        #pragma unroll
        for (int j = 0; j < 2; ++j)
            gld_lds16(Ksw + (tk + j * 256 + t) * 8, &Ks2[b][(j * 256 + w * 64) * 8]);
        #pragma unroll
        for (int j = 0; j < 2; ++j)
            gld_lds16(Vsw + (tk + j * 256 + t) * 8, &Vs2[b][(j * 256 + w * 64) * 8]);
    };

    stage(0, 0);
    stage(1, 1);

    f32x16v accO[2] = {};
    f32x16v accL = {};

    for (int kt = 0; kt < 16; ++kt) {
        if (kt < 15) asm volatile("s_waitcnt vmcnt(4)" ::: "memory");
        else         asm volatile("s_waitcnt vmcnt(0)" ::: "memory");
        __builtin_amdgcn_s_barrier();
        asm volatile("" ::: "memory");
        fa_compute(Ks2[kt & 1], Vs2[kt & 1], H, l31, qf, accO, accL);
        if (kt < 14) {
            __builtin_amdgcn_s_barrier();   // all waves done reading buf kt&1
            asm volatile("" ::: "memory");
            stage(kt + 2, kt & 1);
        }
    }

    // dump partials: accO as bf16 (per-thread 64B), accL f32 (per (w,H), lanes l31==0)
    const int lb = bh * 16 + mblk;
    unsigned int Wd[16];
    #pragma unroll
    for (int nt = 0; nt < 2; ++nt)
        #pragma unroll
        for (int r = 0; r < 16; r += 2)
            Wd[nt * 8 + r / 2] = pkbf(accO[nt][r], accO[nt][r + 1]);
    uint4* od = (uint4*)(Opart + ((size_t)(split * 512 + lb) * 256 + t) * 32);
    od[0] = *(const uint4*)&Wd[0];
    od[1] = *(const uint4*)&Wd[4];
    od[2] = *(const uint4*)&Wd[8];
    od[3] = *(const uint4*)&Wd[12];
    if (l31 == 0) {
        float lv[16];
        #pragma unroll
        for (int r = 0; r < 16; ++r) lv[r] = accL[r];
        float4* ld = (float4*)(Lpart + (((size_t)(split * 512 + lb) * 4 + w) * 2 + H) * 16);
        ld[0] = *(const float4*)&lv[0];
        ld[1] = *(const float4*)&lv[4];
        ld[2] = *(const float4*)&lv[8];
        ld[3] = *(const float4*)&lv[12];
    }
}

// comb_wo (R22): blocks [0,512) = fa_comb (ctx = (O0+O1)/(L0+L1), A/W swizzle);
// blocks [512,768) = cvt3(Wo) into Wot at ws[0,2) (Qb dead after fattn_sp).
// Disjoint reads/writes; block-uniform branch.
__global__ __launch_bounds__(256)
void comb_wo(const unsigned short* __restrict__ Opart, const float* __restrict__ Lpart,
             unsigned short* __restrict__ ctx,
             const float* __restrict__ Wo, unsigned short* __restrict__ Wot) {
    __shared__ __align__(16) unsigned short Ls[64 * 72];
    const int t = threadIdx.x;
    if (blockIdx.x >= 512) {
        const int b = blockIdx.x - 512;      // 256 blocks -> 16x16 tiles
        cvtW_tile(Wo, Wot, Ls, (b >> 4) * 64, (b & 15) * 64, t);
        return;
    }
    const int lb = blockIdx.x;
    const int lane = t & 63, w = t >> 6;
    const int l31 = lane & 31, H = lane >> 5;
    const int bh = lb >> 4, m0 = (lb & 15) * 128;

    const float* L0 = Lpart + (((size_t)lb * 4 + w) * 2 + H) * 16;
    const float* L1 = Lpart + (((size_t)(512 + lb) * 4 + w) * 2 + H) * 16;
    float inv[16];
    #pragma unroll
    for (int r = 0; r < 16; ++r) inv[r] = 1.f / (L0[r] + L1[r]);

    const uint4* o0 = (const uint4*)(Opart + ((size_t)lb * 256 + t) * 32);
    const uint4* o1 = (const uint4*)(Opart + ((size_t)(512 + lb) * 256 + t) * 32);
    unsigned int A0[16], A1[16];
    *(uint4*)&A0[0] = o0[0]; *(uint4*)&A0[4] = o0[1];
    *(uint4*)&A0[8] = o0[2]; *(uint4*)&A0[12] = o0[3];
    *(uint4*)&A1[0] = o1[0]; *(uint4*)&A1[4] = o1[1];
    *(uint4*)&A1[8] = o1[2]; *(uint4*)&A1[12] = o1[3];

    #pragma unroll
    for (int r = 0; r < 16; ++r) {
        const int qloc = (r & 3) + 8 * (r >> 2) + 4 * H;
        const int mrow = (bh >> 4) * 2048 + m0 + w * 32 + qloc;
        #pragma unroll
        for (int nt = 0; nt < 2; ++nt) {
            const int j = nt * 16 + r;
            const unsigned int w0 = A0[j >> 1], w1 = A1[j >> 1];
            const unsigned short h0 = (j & 1) ? (unsigned short)(w0 >> 16) : (unsigned short)(w0 & 0xFFFF);
            const unsigned short h1 = (j & 1) ? (unsigned short)(w1 >> 16) : (unsigned short)(w1 & 0xFFFF);
            const float out = (bf2f(h0) + bf2f(h1)) * inv[r];
            const int k = (bh & 15) * 64 + nt * 32 + l31;
            const size_t g = ((size_t)(mrow >> 7) * 128 + (k >> 3)) * 128 + (mrow & 127);
            ctx[g * 8 + (k & 7)] = f2bf(out);
        }
    }
}

extern "C" void kernel_launch(void* const* d_in, const int* in_sizes, int n_in,
                              void* d_out, int out_size, void* d_ws, size_t ws_size,
                              hipStream_t stream) {
    char* ws = (char*)d_ws;
    unsigned short* Qb    = (unsigned short*)(ws);
    unsigned short* Ksw   = (unsigned short*)(ws + ((size_t)8 << 20));
    unsigned short* Vsw   = (unsigned short*)(ws + ((size_t)16 << 20));
    unsigned short* Wqt   = (unsigned short*)(ws + ((size_t)24 << 20));
    unsigned short* Wkt   = (unsigned short*)(ws + ((size_t)26 << 20));
    unsigned short* Wvt   = (unsigned short*)(ws + ((size_t)28 << 20));
    unsigned short* Aq    = (unsigned short*)(ws + ((size_t)30 << 20));
    unsigned short* Ak    = (unsigned short*)(ws + ((size_t)38 << 20));
    unsigned short* Av    = (unsigned short*)(ws + ((size_t)46 << 20));
    unsigned short* ctx   = (unsigned short*)(ws + ((size_t)24 << 20));  // after QKV GEMM
    unsigned short* Opart = (unsigned short*)(ws + ((size_t)32 << 20));  // overlays dead Aq/Ak
    float*          Lpart = (float*)         (ws + ((size_t)48 << 20));  // overlays dead Av
    unsigned short* Wot   = (unsigned short*)(ws);                        // [0,2): Qb dead after fattn_sp

    prep6<<<dim3(16, 32, 6), 256, 0, stream>>>(
        (const float*)d_in[0], (const float*)d_in[1], (const float*)d_in[2],
        (const float*)d_in[3], (const float*)d_in[4], (const float*)d_in[5],
        Aq, Ak, Av, Wqt, Wkt, Wvt);

    gemm_qkv<<<dim3(768), 256, 0, stream>>>(Aq, Ak, Av, Wqt, Wkt, Wvt,
                                            Qb, Ksw, Vsw, 0.125f * 1.44269504f);

    fattn_sp<<<dim3(1024), 256, 0, stream>>>(Qb, Ksw, Vsw, Opart, Lpart);

    comb_wo<<<dim3(768), 256, 0, stream>>>(Opart, Lpart, ctx, (const float*)d_in[6], Wot);

    gemm_out<<<dim3(512), 256, 0, stream>>>(ctx, Wot, (float*)d_out);
}